// Round 1
// baseline (127.520 us; speedup 1.0000x reference)
//
#include <hip/hip_runtime.h>

// Problem constants (fixed by the reference file)
#define NN   1024      // nodes
#define FD   128       // input features
#define DD1  64        // hidden dim after W1
#define DD2  16        // edge-MLP dim
#define MAXM 16384     // max directed edges (2 * E_HALF)
#define ALPHA_C 0.1f

// Persistent device scratch (rebuilt from inputs every launch; deterministic)
__device__ int   g_T[NN * NN];       // (u,v) -> directed edge id + 1, 0 if no edge
__device__ int   g_deg[NN];
__device__ int   g_off[NN + 1];
__device__ int   g_adj_e[MAXM];      // CSR: directed edge id (u -> v)
__device__ int   g_adj_v[MAXM];      // CSR: neighbor v
__device__ float g_dinv[NN];         // 1/sqrt(deg+1)
__device__ float g_x0[NN * DD1];     // feat@W1+b1
__device__ float g_x1[NN * DD1];
__device__ float g_x2[NN * DD1];     // final propagated features
__device__ float g_xe[MAXM * DD2];   // per-directed-edge MLP outputs
__device__ float g_mul[MAXM * DD2];

// ---------------------------------------------------------------- zero
__global__ void zero_k() {
    int i = blockIdx.x * blockDim.x + threadIdx.x;
    int stride = gridDim.x * blockDim.x;
    for (int j = i; j < NN * NN; j += stride) g_T[j] = 0;
    if (i < NN) g_deg[i] = 0;
}

// ---------------------------------------------------------------- x0 = feat@W1 + b1
__global__ void gemm1_k(const float* __restrict__ feat,
                        const float* __restrict__ W1,
                        const float* __restrict__ b1) {
    int n = blockIdx.x;        // node
    int d = threadIdx.x;       // channel (blockDim = 64)
    const float* fr = feat + n * FD;
    float acc = b1[d];
    #pragma unroll 8
    for (int k = 0; k < FD; ++k) acc += fr[k] * W1[k * DD1 + d];
    g_x0[n * DD1 + d] = acc;
}

// ---------------------------------------------------------------- edge table + degrees
__global__ void build_k(const int* __restrict__ ei0, const int* __restrict__ ei1, int M) {
    int e = blockIdx.x * blockDim.x + threadIdx.x;
    if (e < M) {
        int a = ei0[e], b = ei1[e];
        g_T[a * NN + b] = e + 1;          // unique (a,b) per e -> race-free
        atomicAdd(&g_deg[a], 1);
    }
}

// ---------------------------------------------------------------- exclusive scan of deg (+ dinv)
__global__ void scan_k(int M) {
    __shared__ int s[NN];
    int t = threadIdx.x;                   // blockDim = 1024
    int d = g_deg[t];
    s[t] = d;
    g_dinv[t] = rsqrtf((float)(d + 1));
    __syncthreads();
    for (int ofs = 1; ofs < NN; ofs <<= 1) {
        int v = (t >= ofs) ? s[t - ofs] : 0;
        __syncthreads();
        s[t] += v;
        __syncthreads();
    }
    g_off[t + 1] = s[t];
    if (t == 0) g_off[0] = 0;
}

// ---------------------------------------------------------------- deterministic CSR via ballot-compaction
__global__ void csr_k() {
    int u = blockIdx.x;
    int lane = threadIdx.x;                // blockDim = 64 (one wave)
    int base = g_off[u];
    int cnt = 0;
    for (int c0 = 0; c0 < NN; c0 += 64) {
        int eid = g_T[u * NN + c0 + lane];
        unsigned long long m = __ballot(eid > 0);
        if (eid > 0) {
            int p = __popcll(m & ((1ULL << lane) - 1ULL));
            g_adj_e[base + cnt + p] = eid - 1;
            g_adj_v[base + cnt + p] = c0 + lane;
        }
        cnt += __popcll(m);
    }
}

// ---------------------------------------------------------------- one propagation round
// round 0: x1 = (1-a)*(Ahat@x0) + a*x0 ; round 1: x2 = (1-a)*(Ahat@x1) + a*x0
__global__ void prop_k(int round) {
    int u = blockIdx.x;
    int d = threadIdx.x;                   // blockDim = 64
    const float* xin = (round == 0) ? g_x0 : g_x1;
    float*       xout = (round == 0) ? g_x1 : g_x2;
    int beg = g_off[u], end = g_off[u + 1];
    float acc = 0.f;
    for (int j = beg; j < end; ++j) {
        int v = g_adj_v[j];
        acc += g_dinv[v] * xin[v * DD1 + d];
    }
    float du = g_dinv[u];
    float ah = du * (acc + du * xin[u * DD1 + d]);   // includes self-loop
    xout[u * DD1 + d] = (1.0f - ALPHA_C) * ah + ALPHA_C * g_x0[u * DD1 + d];
}

// ---------------------------------------------------------------- edge MLP: xe, mul per directed edge
__global__ void mlp_k(const int* __restrict__ ei0, const int* __restrict__ ei1,
                      const float* __restrict__ Wm1, const float* __restrict__ bm1,
                      const float* __restrict__ Wm2, const float* __restrict__ bm2,
                      int M) {
    int tid = blockIdx.x * blockDim.x + threadIdx.x;
    if (tid >= M * 32) return;
    int e = tid >> 5;
    int j = tid & 31;
    int m = j & 15;
    const float* W = (j < 16) ? Wm1 : Wm2;
    const float* B = (j < 16) ? bm1 : bm2;
    float*       O = (j < 16) ? g_xe : g_mul;
    int a = ei0[e], b = ei1[e];
    const float* xa = g_x2 + a * DD1;
    const float* xb = g_x2 + b * DD1;
    float acc = B[m];
    #pragma unroll 8
    for (int k = 0; k < DD1; ++k) acc += xa[k] * W[k * DD2 + m];
    #pragma unroll 8
    for (int k = 0; k < DD1; ++k) acc += xb[k] * W[(DD1 + k) * DD2 + m];
    O[e * DD2 + m] = acc;
}

// ---------------------------------------------------------------- per-query-pair phase
__global__ void pair_k(const int* __restrict__ pos,
                       const float* __restrict__ W3, const float* __restrict__ b3,
                       float* __restrict__ out, int P) {
    int p = blockIdx.x * blockDim.x + threadIdx.x;
    if (p >= P) return;
    int u = pos[2 * p], w = pos[2 * p + 1];

    // xx = sum_d x2[u,d]*x2[w,d]
    float xx = 0.f;
    const float* xu = g_x2 + u * DD1;
    const float* xw = g_x2 + w * DD1;
    #pragma unroll 8
    for (int d = 0; d < DD1; ++d) xx += xu[d] * xw[d];

    // prod over common neighbors, both directions
    float p0[DD2], p1[DD2];
    #pragma unroll
    for (int m = 0; m < DD2; ++m) { p0[m] = 0.f; p1[m] = 0.f; }
    bool found = false;
    int s_uw = g_T[u * NN + w];
    int beg = g_off[u], end = g_off[u + 1];
    for (int j = beg; j < end; ++j) {
        int v = g_adj_v[j];
        int t_vw = g_T[v * NN + w];
        if (t_vw > 0) {
            found = true;
            int e_uv = g_adj_e[j];
            int e_vw = t_vw - 1;
            int e_wv = g_T[w * NN + v] - 1;
            int e_vu = g_T[v * NN + u] - 1;
            const float* a0 = g_xe  + e_uv * DD2;
            const float* b0 = g_mul + e_vw * DD2;
            const float* a1 = g_xe  + e_wv * DD2;
            const float* b1v = g_mul + e_vu * DD2;
            #pragma unroll
            for (int m = 0; m < DD2; ++m) {
                p0[m] += a0[m] * b0[m];
                p1[m] += a1[m] * b1v[m];
            }
        }
    }

    float res = xx;
    bool U = found || (s_uw > 0);
    if (U) {
        float se = (s_uw > 0) ? 1.0f : 0.0f;
        float ef = 0.f;
        #pragma unroll
        for (int m = 0; m < DD2; ++m) {
            float base = b3[m] + se * W3[16 * DD2 + m];
            float y0 = base, y1 = base;
            #pragma unroll
            for (int k = 0; k < DD2; ++k) {
                y0 += p0[k] * W3[k * DD2 + m];
                y1 += p1[k] * W3[k * DD2 + m];
            }
            ef += y0 * y1;
        }
        res += ef;
    }
    out[p] = res;
}

// ----------------------------------------------------------------
extern "C" void kernel_launch(void* const* d_in, const int* in_sizes, int n_in,
                              void* d_out, int out_size, void* d_ws, size_t ws_size,
                              hipStream_t stream) {
    const float* feat = (const float*)d_in[0];
    const float* W1   = (const float*)d_in[1];
    const float* b1   = (const float*)d_in[2];
    const float* Wm1  = (const float*)d_in[3];
    const float* bm1  = (const float*)d_in[4];
    const float* Wm2  = (const float*)d_in[5];
    const float* bm2  = (const float*)d_in[6];
    const float* W3   = (const float*)d_in[7];
    const float* b3   = (const float*)d_in[8];
    const int*   ei   = (const int*)d_in[9];
    const int*   pos  = (const int*)d_in[10];
    float* out = (float*)d_out;

    int M = in_sizes[9] / 2;       // directed edges
    int P = in_sizes[10] / 2;      // query pairs
    const int* ei0 = ei;
    const int* ei1 = ei + M;

    zero_k<<<1024, 256, 0, stream>>>();
    gemm1_k<<<NN, DD1, 0, stream>>>(feat, W1, b1);
    build_k<<<(M + 255) / 256, 256, 0, stream>>>(ei0, ei1, M);
    scan_k<<<1, NN, 0, stream>>>(M);
    csr_k<<<NN, 64, 0, stream>>>();
    prop_k<<<NN, DD1, 0, stream>>>(0);
    prop_k<<<NN, DD1, 0, stream>>>(1);
    mlp_k<<<(M * 32 + 255) / 256, 256, 0, stream>>>(ei0, ei1, Wm1, bm1, Wm2, bm2, M);
    pair_k<<<(P + 63) / 64, 64, 0, stream>>>(pos, W3, b3, out, P);
}

// Round 2
// 86.386 us; speedup vs baseline: 1.4762x; 1.4762x over previous
//
#include <hip/hip_runtime.h>

// Problem constants (fixed by the reference file)
#define NN   1024      // nodes
#define FD   128       // input features
#define DD1  64        // hidden dim after W1
#define DD2  16        // edge-MLP dim
#define MAXM 16384     // max directed edges (2 * E_HALF)
#define ALPHA_C 0.1f

// Persistent device scratch (rebuilt from inputs every launch; deterministic)
__device__ int   g_T[NN * NN];       // (u,v) -> directed edge id + 1, 0 if no edge
__device__ int   g_deg[NN];
__device__ int   g_off[NN + 1];
__device__ int   g_adj_e[MAXM];      // CSR: directed edge id (u -> v)
__device__ int   g_adj_v[MAXM];      // CSR: neighbor v
__device__ float g_dinv[NN];         // 1/sqrt(deg+1)
__device__ float g_x0[NN * DD1];     // feat@W1+b1
__device__ float g_x1[NN * DD1];
__device__ float g_x2[NN * DD1];     // final propagated features
__device__ float g_xe[MAXM * DD2];   // per-directed-edge MLP outputs
__device__ float g_mul[MAXM * DD2];

// ------------------------------------------------ init: zero g_T/g_deg + x0 = feat@W1 + b1
// 1024 blocks x 256 threads. Each thread zeros one int4 of g_T; lanes <64 also do the GEMM row.
__global__ void init_k(const float* __restrict__ feat,
                       const float* __restrict__ W1,
                       const float* __restrict__ b1) {
    int b = blockIdx.x;
    int t = threadIdx.x;
    ((int4*)g_T)[b * 256 + t] = make_int4(0, 0, 0, 0);
    if (t == 0) g_deg[b] = 0;
    if (t < DD1) {
        const float* fr = feat + b * FD;
        float acc = b1[t];
        #pragma unroll 8
        for (int k = 0; k < FD; ++k) acc += fr[k] * W1[k * DD1 + t];
        g_x0[b * DD1 + t] = acc;
    }
}

// ------------------------------------------------ edge table + degrees
__global__ void build_k(const int* __restrict__ ei0, const int* __restrict__ ei1, int M) {
    int e = blockIdx.x * blockDim.x + threadIdx.x;
    if (e < M) {
        int a = ei0[e], b = ei1[e];
        g_T[a * NN + b] = e + 1;          // unique (a,b) per e -> race-free
        atomicAdd(&g_deg[a], 1);
    }
}

// ------------------------------------------------ single-wave exclusive scan of deg (+ dinv)
__global__ void scan_k() {
    int lane = threadIdx.x;               // blockDim = 64 (one wave)
    int base = lane * 16;
    int pre[16];
    int s = 0;
    #pragma unroll
    for (int i = 0; i < 16; ++i) {
        int d = g_deg[base + i];
        g_dinv[base + i] = rsqrtf((float)(d + 1));
        pre[i] = s;
        s += d;
    }
    int inc = s;
    #pragma unroll
    for (int o = 1; o < 64; o <<= 1) {
        int t = __shfl_up(inc, o);
        if (lane >= o) inc += t;
    }
    int excl = inc - s;
    #pragma unroll
    for (int i = 0; i < 16; ++i) g_off[base + i] = excl + pre[i];
    if (lane == 63) g_off[NN] = excl + s;
}

// ------------------------------------------------ deterministic CSR via ballot-compaction
__global__ void csr_k() {
    int u = blockIdx.x;
    int lane = threadIdx.x;                // blockDim = 64 (one wave)
    int base = g_off[u];
    int cnt = 0;
    for (int c0 = 0; c0 < NN; c0 += 64) {
        int eid = g_T[u * NN + c0 + lane];
        unsigned long long m = __ballot(eid > 0);
        if (eid > 0) {
            int p = __popcll(m & ((1ULL << lane) - 1ULL));
            g_adj_e[base + cnt + p] = eid - 1;
            g_adj_v[base + cnt + p] = c0 + lane;
        }
        cnt += __popcll(m);
    }
}

// ------------------------------------------------ one propagation round
// round 0: x1 = (1-a)*(Ahat@x0) + a*x0 ; round 1: x2 = (1-a)*(Ahat@x1) + a*x0
__global__ void prop_k(int round) {
    int u = blockIdx.x;
    int d = threadIdx.x;                   // blockDim = 64
    const float* xin = (round == 0) ? g_x0 : g_x1;
    float*       xout = (round == 0) ? g_x1 : g_x2;
    int beg = g_off[u], end = g_off[u + 1];
    float acc = 0.f;
    for (int j = beg; j < end; ++j) {
        int v = g_adj_v[j];
        acc += g_dinv[v] * xin[v * DD1 + d];
    }
    float du = g_dinv[u];
    float ah = du * (acc + du * xin[u * DD1 + d]);   // includes self-loop
    xout[u * DD1 + d] = (1.0f - ALPHA_C) * ah + ALPHA_C * g_x0[u * DD1 + d];
}

// ------------------------------------------------ edge MLP: xe, mul per directed edge
__global__ void mlp_k(const int* __restrict__ ei0, const int* __restrict__ ei1,
                      const float* __restrict__ Wm1, const float* __restrict__ bm1,
                      const float* __restrict__ Wm2, const float* __restrict__ bm2,
                      int M) {
    int tid = blockIdx.x * blockDim.x + threadIdx.x;
    if (tid >= M * 32) return;
    int e = tid >> 5;
    int j = tid & 31;
    int m = j & 15;
    const float* W = (j < 16) ? Wm1 : Wm2;
    const float* B = (j < 16) ? bm1 : bm2;
    float*       O = (j < 16) ? g_xe : g_mul;
    int a = ei0[e], b = ei1[e];
    const float* xa = g_x2 + a * DD1;
    const float* xb = g_x2 + b * DD1;
    float acc = B[m];
    #pragma unroll 8
    for (int k = 0; k < DD1; ++k) acc += xa[k] * W[k * DD2 + m];
    #pragma unroll 8
    for (int k = 0; k < DD1; ++k) acc += xb[k] * W[(DD1 + k) * DD2 + m];
    O[e * DD2 + m] = acc;
}

// ------------------------------------------------ per-query-pair phase, 16 lanes per pair
// lane m owns channel m; 16 neighbors' g_T gathers issued concurrently.
__global__ void pair_k(const int* __restrict__ pos,
                       const float* __restrict__ W3, const float* __restrict__ b3,
                       float* __restrict__ out, int P) {
    int lane = threadIdx.x & 63;
    int grp  = lane >> 4;                  // 4 pair-groups per wave
    int m    = lane & 15;
    int wave = (blockIdx.x * blockDim.x + threadIdx.x) >> 6;
    int p = wave * 4 + grp;
    if (p >= P) return;
    int u = pos[2 * p], w = pos[2 * p + 1];

    // xx = x2[u] . x2[w]  (16-lane split + reduce)
    const float* xu = g_x2 + u * DD1;
    const float* xw = g_x2 + w * DD1;
    float xx = 0.f;
    #pragma unroll
    for (int d = m; d < DD1; d += 16) xx += xu[d] * xw[d];
    #pragma unroll
    for (int o = 8; o; o >>= 1) xx += __shfl_xor(xx, o);

    // common-neighbor products: lane m prefetches neighbor j0+m's lookups
    float p0 = 0.f, p1 = 0.f;
    bool found = false;
    int beg = g_off[u], end = g_off[u + 1];
    for (int j0 = beg; j0 < end; j0 += 16) {
        int j = j0 + m;
        int t_vw = 0, e_uv = 0, e_wv = 0, e_vu = 0;
        if (j < end) {
            int v  = g_adj_v[j];
            e_uv   = g_adj_e[j];
            t_vw   = g_T[v * NN + w];
            e_vu   = g_T[v * NN + u] - 1;
            e_wv   = g_T[w * NN + v] - 1;   // valid iff t_vw > 0
        }
        unsigned long long mask = __ballot(t_vw > 0);
        unsigned long long gm = (mask >> (grp * 16)) & 0xFFFFULL;
        if (gm) found = true;
        while (gm) {
            int k = __ffsll(gm) - 1;
            gm &= gm - 1;
            int src = grp * 16 + k;
            int a0 = __shfl(e_uv, src);
            int b0 = __shfl(t_vw, src) - 1;
            int a1 = __shfl(e_wv, src);
            int b1 = __shfl(e_vu, src);
            p0 += g_xe[a0 * DD2 + m] * g_mul[b0 * DD2 + m];
            p1 += g_xe[a1 * DD2 + m] * g_mul[b1 * DD2 + m];
        }
    }

    int s_uw = g_T[u * NN + w];
    float res = xx;
    if (found || s_uw > 0) {
        float se = (s_uw > 0) ? 1.0f : 0.0f;
        float base = b3[m] + se * W3[16 * DD2 + m];
        float y0 = base, y1 = base;
        #pragma unroll
        for (int k = 0; k < DD2; ++k) {
            float wk  = W3[k * DD2 + m];
            float p0k = __shfl(p0, grp * 16 + k);
            float p1k = __shfl(p1, grp * 16 + k);
            y0 += p0k * wk;
            y1 += p1k * wk;
        }
        float ef = y0 * y1;
        #pragma unroll
        for (int o = 8; o; o >>= 1) ef += __shfl_xor(ef, o);
        res += ef;
    }
    if (m == 0) out[p] = res;
}

// ----------------------------------------------------------------
extern "C" void kernel_launch(void* const* d_in, const int* in_sizes, int n_in,
                              void* d_out, int out_size, void* d_ws, size_t ws_size,
                              hipStream_t stream) {
    const float* feat = (const float*)d_in[0];
    const float* W1   = (const float*)d_in[1];
    const float* b1   = (const float*)d_in[2];
    const float* Wm1  = (const float*)d_in[3];
    const float* bm1  = (const float*)d_in[4];
    const float* Wm2  = (const float*)d_in[5];
    const float* bm2  = (const float*)d_in[6];
    const float* W3   = (const float*)d_in[7];
    const float* b3   = (const float*)d_in[8];
    const int*   ei   = (const int*)d_in[9];
    const int*   pos  = (const int*)d_in[10];
    float* out = (float*)d_out;

    int M = in_sizes[9] / 2;       // directed edges
    int P = in_sizes[10] / 2;      // query pairs
    const int* ei0 = ei;
    const int* ei1 = ei + M;

    init_k<<<NN, 256, 0, stream>>>(feat, W1, b1);
    build_k<<<(M + 255) / 256, 256, 0, stream>>>(ei0, ei1, M);
    scan_k<<<1, 64, 0, stream>>>();
    csr_k<<<NN, 64, 0, stream>>>();
    prop_k<<<NN, DD1, 0, stream>>>(0);
    prop_k<<<NN, DD1, 0, stream>>>(1);
    mlp_k<<<(M * 32 + 255) / 256, 256, 0, stream>>>(ei0, ei1, Wm1, bm1, Wm2, bm2, M);
    pair_k<<<(P * 16 + 255) / 256, 256, 0, stream>>>(pos, W3, b3, out, P);
}